// Round 1
// baseline (108.464 us; speedup 1.0000x reference)
//
#include <hip/hip_runtime.h>

// SPU bound transformer: element-wise over (N,2) fp32 rows.
// Memory-bound: 67 MB in + 67 MB out. float4 = 2 rows per thread.

__device__ __forceinline__ float spu_f(float x) {
    // x >= 0: x*x - 0.5
    // x <  0: sigmoid(-x) - 1 = -e^x / (1 + e^x)
    float t = __expf(x);
    float negbr = -t / (1.0f + t);
    float posbr = __fmaf_rn(x, x, -0.5f);
    return (x >= 0.0f) ? posbr : negbr;
}

__device__ __forceinline__ void spu_row(float l, float u, float& lower, float& upper) {
    float vl = spu_f(l);
    float vu = spu_f(u);
    float slope = (vu - vl) / (u - l);   // only consumed when l < 0 < u (u-l > 0)
    bool neg   = (u <= 0.0f);
    bool pos   = (l >= 0.0f);
    bool cross = !(neg || pos);
    bool cpos  = cross && (slope >= 0.0f);
    bool cneg  = cross && (slope < 0.0f);
    lower = neg ? vl : (cpos ? -0.5f : 0.0f);
    upper = neg ? vu : (cpos ? vu : (cneg ? vl : 0.0f));
}

__global__ __launch_bounds__(256) void spu_kernel(const float4* __restrict__ in,
                                                  float4* __restrict__ out,
                                                  int n4) {
    int i = blockIdx.x * blockDim.x + threadIdx.x;
    if (i >= n4) return;
    float4 v = in[i];           // two rows: (l0,u0,l1,u1)
    float4 r;
    spu_row(v.x, v.y, r.x, r.y);
    spu_row(v.z, v.w, r.z, r.w);
    out[i] = r;
}

extern "C" void kernel_launch(void* const* d_in, const int* in_sizes, int n_in,
                              void* d_out, int out_size, void* d_ws, size_t ws_size,
                              hipStream_t stream) {
    const float4* in = (const float4*)d_in[0];
    float4* out = (float4*)d_out;
    int n4 = out_size / 4;                 // 8388608*2 floats / 4 = 4194304
    int threads = 256;
    int blocks = (n4 + threads - 1) / threads;
    spu_kernel<<<blocks, threads, 0, stream>>>(in, out, n4);
}